// Round 2
// baseline (191.700 us; speedup 1.0000x reference)
//
#include <hip/hip_runtime.h>

typedef unsigned long long u64;

#define NIMG 4
#define H 256
#define W 256
#define NPIX (H*W)           // 65536 per image
#define NTOT (NIMG*NPIX)     // 262144
#define WPR 4                // u64 words per row (256 bits)
#define WPI (H*WPR)          // 1024 words per image
#define WPB (NIMG*WPI)       // 4096 words per branch
#define XT 16                // columns per edt tile block
#define NSKEL 8              // skeleton blocks (1 per branch-image)
#define NEDT 128             // edt tile blocks
#define NB1 (NSKEL+NEDT)     // 136 blocks in kernel 1

// ---------------------------------------------------------------------------
// Bit-parallel morphology helpers. Bit b of word k = pixel x = 64k+b.
// Erode = AND over cross {c, up, down, left, right}, OOB treated as 1.
// Dilate = OR over 3x3 box, OOB treated as 0.
// ---------------------------------------------------------------------------
__device__ __forceinline__ void erode_from(const u64 S[][WPR], int y, u64 out[WPR]) {
  u64 c[WPR], up[WPR], dn[WPR];
#pragma unroll
  for (int k = 0; k < WPR; ++k) {
    c[k]  = S[y][k];
    up[k] = (y > 0)     ? S[y-1][k] : ~0ULL;
    dn[k] = (y < H-1)   ? S[y+1][k] : ~0ULL;
  }
#pragma unroll
  for (int k = 0; k < WPR; ++k) {
    u64 l = (c[k] << 1) | ((k > 0)     ? (c[k-1] >> 63) : 1ULL);
    u64 r = (c[k] >> 1) | ((k < WPR-1) ? (c[k+1] << 63) : 0x8000000000000000ULL);
    out[k] = c[k] & up[k] & dn[k] & l & r;
  }
}

__device__ __forceinline__ void dilate_from(const u64 S[][WPR], int y, u64 out[WPR]) {
  u64 v[WPR];
#pragma unroll
  for (int k = 0; k < WPR; ++k) {
    u64 a = S[y][k];
    if (y > 0)   a |= S[y-1][k];
    if (y < H-1) a |= S[y+1][k];
    v[k] = a;
  }
#pragma unroll
  for (int k = 0; k < WPR; ++k) {
    u64 l = (v[k] << 1) | ((k > 0)     ? (v[k-1] >> 63) : 0ULL);
    u64 r = (v[k] >> 1) | ((k < WPR-1) ? (v[k+1] << 63) : 0ULL);
    out[k] = v[k] | l | r;
  }
}

// ---------------------------------------------------------------------------
// K1: 136 blocks x 256 threads, PLAIN launch (no grid.sync — round 1 showed
// cooperative sync costs ~19us each on 8-XCD gfx950).
//  Every block first rebuilds its image's bitmask in LDS from the RAW inputs
//  (true mask: y_true>0; pred hard mask: q>0.5 with q recomputed — identical
//  float expression everywhere => identical bits). This kills the prep kernel
//  and the pp/mask_bits global buffers.
//  blocks 0..7    : 10-iter bit-packed soft_skel in LDS -> skel_bits.
//  blocks 8..135  : EDT distances for a 16-column tile -> edt.
//  Skel's serial 22-barrier chain hides under the 128 EDT blocks.
// ---------------------------------------------------------------------------
__global__ void __launch_bounds__(256, 1) morpho_kernel(
    const float* __restrict__ y_pred, const int* __restrict__ y_true,
    u64* __restrict__ skel_bits, float* __restrict__ edt,
    double* __restrict__ sums, unsigned* __restrict__ done_cnt) {
  __shared__ u64 SA[H][WPR];
  __shared__ u64 SB[H][WPR];
  __shared__ float col2[H][XT + 1];   // pad 17: 2-way aliasing is free on gfx950
  int t = threadIdx.x;
  bool is_skel = blockIdx.x < NSKEL;
  int bi = is_skel ? blockIdx.x : ((blockIdx.x - NSKEL) >> 4);  // branch*4+img

  if (blockIdx.x == 0) {              // init for K3 (separated by boundaries)
    if (t < 4) sums[t] = 0.0;
    else if (t == 4) *done_cnt = 0u;
  }

  // ---- build mask bits for image bi into SA (ballot: wave = 64 consec px) ----
  u64* SAf = &SA[0][0];
  if (bi < 4) {
    const int* src = y_true + bi * NPIX;
#pragma unroll 4
    for (int it = 0; it < NPIX / 256; ++it) {
      int pix = it * 256 + t;
      u64 bb = __ballot(src[pix] > 0);
      if ((t & 63) == 0) SAf[pix >> 6] = bb;
    }
  } else {
    const float* src = y_pred + (bi - 4) * NPIX;
#pragma unroll 2
    for (int it = 0; it < NPIX / 256; ++it) {
      int pix = it * 256 + t;
      float x = src[pix];
      float p = 1.0f / (1.0f + expf(-x));
      float q = 1.0f / (1.0f + expf(-(2.0f * p - 1.0f)));
      u64 bb = __ballot(q > 0.5f);
      if ((t & 63) == 0) SAf[pix >> 6] = bb;
    }
  }
  __syncthreads();

  if (is_skel) {
    // --- soft_skel, bit-packed, 1 thread per row, ONE barrier per level ---
    int y = t;
    int base = bi * WPI;
    u64 a[WPR], cur[WPR], e[WPR], d[WPR], sk[WPR];
#pragma unroll
    for (int k = 0; k < WPR; ++k) a[k] = SA[y][k];
    erode_from(SA, y, e);                 // E1 = erode(a)
#pragma unroll
    for (int k = 0; k < WPR; ++k) SB[y][k] = e[k];
    __syncthreads();                      // SB visible; all SA reads complete
    dilate_from(SB, y, d);                // open(a)
#pragma unroll
    for (int k = 0; k < WPR; ++k) { sk[k] = a[k] & ~d[k]; cur[k] = e[k]; }
    u64 (*P)[WPR] = SB;                   // current erosion level E_k
    u64 (*Q)[WPR] = SA;                   // dead buffer
    for (int it = 0; it < 10; ++it) {     // levels 1..10
      erode_from(P, y, e);                // E_{k+1}
#pragma unroll
      for (int k = 0; k < WPR; ++k) Q[y][k] = e[k];   // overwrite dead data
      __syncthreads();                    // publish Q; P reads all done
      dilate_from(Q, y, d);               // open(E_k)
#pragma unroll
      for (int k = 0; k < WPR; ++k) { sk[k] |= cur[k] & ~d[k]; cur[k] = e[k]; }
      u64 (*T)[WPR] = P; P = Q; Q = T;
    }
#pragma unroll
    for (int k = 0; k < WPR; ++k) skel_bits[base + y*WPR + k] = sk[k];
  } else {
    // --- EDT distances for tile (bi, xt), mask read from LDS ---
    int xt = (blockIdx.x - NSKEL) & 15;
    int x0 = xt * XT;
    int kx = x0 >> 6;                    // all tile columns in this u64 word
    // phase 1: thread = row y; horizontal EDT g via clz/ctz -> col2 = g^2
    {
      int y = t;
      u64 z[WPR];
#pragma unroll
      for (int k = 0; k < WPR; ++k) z[k] = ~SA[y][k];   // background bits
#pragma unroll
      for (int xx = 0; xx < XT; ++xx) {
        int x = x0 + xx;
        int bx = x & 63;
        int ld = 512;
        {
          u64 w = z[kx] & ((bx == 63) ? ~0ULL : ((1ULL << (bx+1)) - 1ULL));
          for (int k = kx; ; ) {
            if (w) { int pos = 63 - __builtin_clzll(w) + (k << 6); ld = x - pos; break; }
            if (--k < 0) break;
            w = z[k];
          }
        }
        int rd = 512;
        {
          u64 w = z[kx] & (~0ULL << bx);
          for (int k = kx; ; ) {
            if (w) { int pos = __builtin_ctzll(w) + (k << 6); rd = pos - x; break; }
            if (++k > WPR-1) break;
            w = z[k];
          }
        }
        int g = min(ld, rd);
        col2[y][xx] = (float)(g * g);
      }
    }
    __syncthreads();
    // phase 2: thread = (x in tile, ygrp of 16 rows); early-exit envelope
    int x  = t & (XT - 1);
    int yg = t >> 4;
#pragma unroll
    for (int j = 0; j < 16; ++j) {
      int y = yg * 16 + j;
      float best = col2[y][x];
      for (int k = 1; k < H; ++k) {
        float k2 = (float)(k * k);
        if (k2 >= best) break;           // no farther candidate can improve
        int ym = y - k, yq = y + k;
        if (ym >= 0) best = fminf(best, col2[ym][x] + k2);
        if (yq < H)  best = fminf(best, col2[yq][x] + k2);
      }
      edt[bi*NPIX + y*W + x0 + x] = sqrtf(best);
    }
  }
}

// ---------------------------------------------------------------------------
// K2: rmax/rmin per (branch,image). 8 blocks x 1024 threads, 64 px/thread.
// Single block per image => direct stores, NO atomics, NO init dependency.
// ---------------------------------------------------------------------------
__global__ void __launch_bounds__(1024, 1) rmm_kernel(
    const u64* __restrict__ skel_bits, const float* __restrict__ edt,
    float* __restrict__ rmm_f) {
  int bi = blockIdx.x;
  int t = threadIdx.x;
  const float* e = edt + bi * NPIX;
  const u64* sb = skel_bits + bi * WPI;
  float vmax = 0.0f, vmin = 3.0e38f;
#pragma unroll 4
  for (int it = 0; it < NPIX / 1024; ++it) {
    int pix = it * 1024 + t;
    float dist = e[pix];
    u64 sw = sb[pix >> 6];
    int bit = (int)((sw >> (pix & 63)) & 1ULL);
    float srad = bit ? dist : 0.0f;      // skel_radius (0 off-skel, like ref)
    vmax = fmaxf(vmax, srad);
    vmin = fminf(vmin, srad);
  }
  for (int o = 32; o > 0; o >>= 1) {
    vmax = fmaxf(vmax, __shfl_down(vmax, o, 64));
    vmin = fminf(vmin, __shfl_down(vmin, o, 64));
  }
  __shared__ float smax[16], smin[16];
  int wave = t >> 6, lane = t & 63;
  if (lane == 0) { smax[wave] = vmax; smin[wave] = vmin; }
  __syncthreads();
  if (t == 0) {
    float mx = smax[0], mn = smin[0];
    for (int wv = 1; wv < 16; ++wv) { mx = fmaxf(mx, smax[wv]); mn = fminf(mn, smin[wv]); }
    rmm_f[bi*2 + 0] = mx;
    rmm_f[bi*2 + 1] = mn;
  }
}

// ---------------------------------------------------------------------------
// K3: q terms + sums + finalize. 128 blocks x 256 threads, 8 px/thread.
// pp recomputed from y_pred (bit-identical expression); masks from raw
// inputs; last-done block (device-scope atomics, proven scheme) writes loss.
// ---------------------------------------------------------------------------
__global__ void __launch_bounds__(256, 1) final_kernel(
    const float* __restrict__ y_pred, const int* __restrict__ y_true,
    const u64* __restrict__ skel_bits, const float* __restrict__ edt,
    const float* __restrict__ rmm_f, double* __restrict__ sums,
    unsigned* __restrict__ done_cnt, float* __restrict__ out) {
  int t = threadIdx.x;
  int i0 = (blockIdx.x * 256 + t) * 8;   // 8 px/thread, same u64 word
  int img = i0 >> 16;
  int wi  = i0 >> 6;
  int b0  = i0 & 63;                     // b0 <= 56: 8 bits in same word
  u64 sw_t = skel_bits[wi];
  u64 sw_p = skel_bits[WPB + wi];
  float4 xp0 = *(const float4*)(y_pred + i0);
  float4 xp1 = *(const float4*)(y_pred + i0 + 4);
  int4   yt0 = *(const int4*)(y_true + i0);
  int4   yt1 = *(const int4*)(y_true + i0 + 4);
  float4 dt0 = *(const float4*)(edt + i0);
  float4 dt1 = *(const float4*)(edt + i0 + 4);
  float4 dp0 = *(const float4*)(edt + NTOT + i0);
  float4 dp1 = *(const float4*)(edt + NTOT + i0 + 4);
  float rmax_t = fmaxf(rmm_f[img*2 + 0], 1.0f);
  float rmin_t = fmaxf(rmm_f[img*2 + 1], 1.0f);
  float rmax_p = fmaxf(rmm_f[(4+img)*2 + 0], 1.0f);
  float rmin_p = fmaxf(rmm_f[(4+img)*2 + 1], 1.0f);
  float xs[8] = {xp0.x,xp0.y,xp0.z,xp0.w,xp1.x,xp1.y,xp1.z,xp1.w};
  int   ms[8] = {yt0.x,yt0.y,yt0.z,yt0.w,yt1.x,yt1.y,yt1.z,yt1.w};
  float dts[8] = {dt0.x,dt0.y,dt0.z,dt0.w,dt1.x,dt1.y,dt1.z,dt1.w};
  float dps[8] = {dp0.x,dp0.y,dp0.z,dp0.w,dp1.x,dp1.y,dp1.z,dp1.w};
  float q1 = 0.f, q2 = 0.f, q3 = 0.f, q4 = 0.f;
#pragma unroll
  for (int j = 0; j < 8; ++j) {
    int b = b0 + j;
    // pp recomputed — identical float expression to reference composition
    float p = 1.0f / (1.0f + expf(-xs[j]));
    float ppv = 1.0f / (1.0f + expf(-(2.0f * p - 1.0f)));
    // --- true branch (binary) ---
    int m_t = ms[j] > 0 ? 1 : 0;
    int s_t = (int)((sw_t >> b) & 1ULL);
    float distances_t = m_t ? dts[j] : 0.0f;
    float skelrad_t   = s_t ? distances_t : 0.0f;
    float dmn_t = fminf(distances_t, rmax_t) / rmax_t;
    float srn_t = skelrad_t / rmax_t;
    float In_t  = s_t ? (rmax_t - skelrad_t + rmin_t) / rmax_t : 0.0f;
    float q_vl   = m_t ? dmn_t : 0.0f;
    float q_slvl = m_t ? srn_t : 0.0f;
    float q_sl   = s_t ? In_t  : 0.0f;
    // --- pred branch (probabilistic) ---
    int s_pb = (int)((sw_p >> b) & 1ULL);
    float skel_in_p = s_pb ? ppv : 0.0f;      // skel_pred_prob
    bool msk_p = ppv > 0.5f;
    bool sk_p  = skel_in_p > 0.5f;
    float distances_p = msk_p ? dps[j] : 0.0f;
    float skelrad_p   = sk_p ? distances_p : 0.0f;
    float dmn_p = fminf(distances_p, rmax_p) / rmax_p;
    float srn_p = skelrad_p / rmax_p;
    float In_p  = sk_p ? (rmax_p - skelrad_p + rmin_p) / rmax_p : 0.0f;
    float q_vp   = dmn_p * ppv;
    float q_spvp = srn_p * ppv;
    float q_sp   = In_p * skel_in_p;
    q1 += q_sp * q_vl;
    q2 += (q_spvp != 0.0f && q_slvl == 0.0f) ? q_spvp * q_sp : q_slvl * q_sp;
    q3 += q_sl * q_vp;
    q4 += (q_slvl != 0.0f && q_spvp == 0.0f) ? q_slvl * q_sl : q_spvp * q_sl;
  }
  for (int o = 32; o > 0; o >>= 1) {
    q1 += __shfl_down(q1, o, 64);
    q2 += __shfl_down(q2, o, 64);
    q3 += __shfl_down(q3, o, 64);
    q4 += __shfl_down(q4, o, 64);
  }
  __shared__ float part[4][4];
  int wave = t >> 6, lane = t & 63;
  if (lane == 0) { part[wave][0]=q1; part[wave][1]=q2; part[wave][2]=q3; part[wave][3]=q4; }
  __syncthreads();
  if (t == 0) {
    float a0=0,a1=0,a2=0,a3=0;
    for (int wv = 0; wv < 4; ++wv) {
      a0 += part[wv][0]; a1 += part[wv][1]; a2 += part[wv][2]; a3 += part[wv][3];
    }
    atomicAdd(&sums[0], (double)a0);
    atomicAdd(&sums[1], (double)a1);
    atomicAdd(&sums[2], (double)a2);
    atomicAdd(&sums[3], (double)a3);
    __threadfence();                    // publish sums before counting done
    unsigned c = atomicAdd(done_cnt, 1u);
    if (c == NEDT - 1) {                // last block finalizes (device-scope
      double s0 = atomicAdd(&sums[0], 0.0);   // atomic loads for coherence)
      double s1 = atomicAdd(&sums[1], 0.0);
      double s2 = atomicAdd(&sums[2], 0.0);
      double s3 = atomicAdd(&sums[3], 0.0);
      double wp  = (s0 + 1.0) / (s1 + 1.0);
      double wsn = (s2 + 1.0) / (s3 + 1.0);
      out[0] = (float)(1.0 - 2.0 * (wp * wsn) / (wp + wsn));
    }
  }
}

extern "C" void kernel_launch(void* const* d_in, const int* in_sizes, int n_in,
                              void* d_out, int out_size, void* d_ws, size_t ws_size,
                              hipStream_t stream) {
  (void)in_sizes; (void)n_in; (void)out_size; (void)ws_size;
  const float* y_pred = (const float*)d_in[0];
  const int*   y_true = (const int*)d_in[1];
  float* out = (float*)d_out;
  char* ws = (char*)d_ws;

  // workspace layout (bytes)
  float* edt       = (float*)(ws + 0);          // 524288 f (2,097,152 B) [branch][img][y][x]
  u64*   skel_bits = (u64*)  (ws + 2097152);    // 8192 u64 (65,536 B)
  float* rmm_f     = (float*)(ws + 2162688);    // 16 f
  double* sums     = (double*)(ws + 2162752);   // 4 d
  unsigned* done_cnt = (unsigned*)(ws + 2162784); // 1 u32

  morpho_kernel<<<NB1, 256, 0, stream>>>(y_pred, y_true, skel_bits, edt, sums, done_cnt);
  rmm_kernel<<<NSKEL, 1024, 0, stream>>>(skel_bits, edt, rmm_f);
  final_kernel<<<NEDT, 256, 0, stream>>>(y_pred, y_true, skel_bits, edt, rmm_f, sums, done_cnt, out);
}

// Round 3
// 102.702 us; speedup vs baseline: 1.8666x; 1.8666x over previous
//
#include <hip/hip_runtime.h>

typedef unsigned long long u64;

#define NIMG 4
#define H 256
#define W 256
#define NPIX (H*W)           // 65536 per image
#define NTOT (NIMG*NPIX)     // 262144
#define WPR 4                // u64 words per row (256 bits)
#define WPI (H*WPR)          // 1024 words per image
#define WPB (NIMG*WPI)       // 4096 words per branch
#define XT 16                // columns per edt tile block
#define NSKEL 8              // skeleton blocks (1 per branch-image)
#define NEDT 128             // edt tile blocks
#define NB2 (NSKEL+NEDT)     // 136 blocks in kernel 2 (all co-resident on 256 CUs)
#define NB3 (NTOT/1024)      // 256 blocks in kernel 3

// ---------------------------------------------------------------------------
// Bit-parallel morphology helpers. Bit b of word k = pixel x = 64k+b.
// Erode = AND over cross {c, up, down, left, right}, OOB treated as 1.
// Dilate = OR over 3x3 box, OOB treated as 0.
// ---------------------------------------------------------------------------
__device__ __forceinline__ void erode_from(const u64 S[][WPR], int y, u64 out[WPR]) {
  u64 c[WPR], up[WPR], dn[WPR];
#pragma unroll
  for (int k = 0; k < WPR; ++k) {
    c[k]  = S[y][k];
    up[k] = (y > 0)     ? S[y-1][k] : ~0ULL;
    dn[k] = (y < H-1)   ? S[y+1][k] : ~0ULL;
  }
#pragma unroll
  for (int k = 0; k < WPR; ++k) {
    u64 l = (c[k] << 1) | ((k > 0)     ? (c[k-1] >> 63) : 1ULL);
    u64 r = (c[k] >> 1) | ((k < WPR-1) ? (c[k+1] << 63) : 0x8000000000000000ULL);
    out[k] = c[k] & up[k] & dn[k] & l & r;
  }
}

__device__ __forceinline__ void dilate_from(const u64 S[][WPR], int y, u64 out[WPR]) {
  u64 v[WPR];
#pragma unroll
  for (int k = 0; k < WPR; ++k) {
    u64 a = S[y][k];
    if (y > 0)   a |= S[y-1][k];
    if (y < H-1) a |= S[y+1][k];
    v[k] = a;
  }
#pragma unroll
  for (int k = 0; k < WPR; ++k) {
    u64 l = (v[k] << 1) | ((k > 0)     ? (v[k-1] >> 63) : 0ULL);
    u64 r = (v[k] >> 1) | ((k < WPR-1) ? (v[k+1] << 63) : 0ULL);
    out[k] = v[k] | l | r;
  }
}

// ---------------------------------------------------------------------------
// K1: prep — round-0 structure (proven fast: NO per-thread loop, 4096 waves,
// one load+ballot each; round 2 showed looped ballot chains are a latency
// disaster). pp = sigmoid(2*sigmoid(x)-1); pack yt and (pp>0.5) bitmasks.
// Block 0 inits sums + handshake counters.
// ---------------------------------------------------------------------------
__global__ void __launch_bounds__(256) prep_kernel(
    const float* __restrict__ y_pred, const int* __restrict__ y_true,
    float* __restrict__ pp, u64* __restrict__ mask_bits,
    double* __restrict__ sums, unsigned* __restrict__ cnts) {
  if (blockIdx.x == 0) {
    if (threadIdx.x < 4) sums[threadIdx.x] = 0.0;
    else if (threadIdx.x < 13) cnts[threadIdx.x - 4] = 0u;  // 8 edt_done + done
  }
  int i = blockIdx.x * 256 + threadIdx.x;
  float x = y_pred[i];
  float p = 1.0f / (1.0f + expf(-x));
  float q = 1.0f / (1.0f + expf(-(2.0f * p - 1.0f)));
  pp[i] = q;
  u64 bt = __ballot(y_true[i] > 0);
  u64 bp = __ballot(q > 0.5f);
  if ((threadIdx.x & 63) == 0) {
    mask_bits[i >> 6] = bt;          // branch 0: true mask
    mask_bits[WPB + (i >> 6)] = bp;  // branch 1: pred hard mask (pp>0.5)
  }
}

// ---------------------------------------------------------------------------
// K2: 136 blocks x 256 threads, plain launch.
//  blocks 0..7    : 10-iter bit-packed soft_skel in LDS (mask read from
//                   global bitmask — 32 B/thread coalesced, NOT rebuilt).
//                   After writing skel_bits: spin on the image's edt_done
//                   counter (device-scope acquire), then compute rmax/rmin
//                   with coalesced float4 edt reads + in-LDS skel bits.
//                   One block per image => direct rmm_f stores, no atomics.
//  blocks 8..135  : EDT distances for a 16-column tile -> edt; then
//                   release-fence + atomicAdd(edt_done[bi]).
//  Skel's serial 22-barrier chain hides under the 128 EDT blocks; the rmm
//  tail costs ~2 us after the image's last tile. All 136 blocks co-resident
//  (<=256 CUs) => spin-wait is deadlock-free.
// ---------------------------------------------------------------------------
__global__ void __launch_bounds__(256, 1) morpho_kernel(
    const u64* __restrict__ mask_bits, u64* __restrict__ skel_bits,
    float* __restrict__ edt, float* __restrict__ rmm_f,
    unsigned* __restrict__ cnts) {
  __shared__ u64 SA[H][WPR];
  __shared__ u64 SB[H][WPR];
  __shared__ float col2[H][XT + 1];   // pad 17: 2-way aliasing free on gfx950
  __shared__ float smax[4], smin[4];
  int t = threadIdx.x;

  if (blockIdx.x < NSKEL) {
    // --- soft_skel, bit-packed, 1 thread per row, ONE barrier per level ---
    int bi = blockIdx.x;
    int y = t;
    int base = bi * WPI;
    u64 a[WPR], cur[WPR], e[WPR], d[WPR], sk[WPR];
#pragma unroll
    for (int k = 0; k < WPR; ++k) { a[k] = mask_bits[base + y*WPR + k]; SA[y][k] = a[k]; }
    __syncthreads();
    erode_from(SA, y, e);                 // E1 = erode(a)
#pragma unroll
    for (int k = 0; k < WPR; ++k) SB[y][k] = e[k];
    __syncthreads();                      // SB visible; all SA reads complete
    dilate_from(SB, y, d);                // open(a)
#pragma unroll
    for (int k = 0; k < WPR; ++k) { sk[k] = a[k] & ~d[k]; cur[k] = e[k]; }
    u64 (*P)[WPR] = SB;                   // current erosion level E_k
    u64 (*Q)[WPR] = SA;                   // dead buffer
    for (int it = 0; it < 10; ++it) {     // levels 1..10
      erode_from(P, y, e);                // E_{k+1}
#pragma unroll
      for (int k = 0; k < WPR; ++k) Q[y][k] = e[k];   // overwrite dead data
      __syncthreads();                    // publish Q; P reads all done
      dilate_from(Q, y, d);               // open(E_k)
#pragma unroll
      for (int k = 0; k < WPR; ++k) { sk[k] |= cur[k] & ~d[k]; cur[k] = e[k]; }
      u64 (*T)[WPR] = P; P = Q; Q = T;
    }
#pragma unroll
    for (int k = 0; k < WPR; ++k) skel_bits[base + y*WPR + k] = sk[k];
    // --- publish skel bits to LDS for the rmm tail ---
    __syncthreads();                      // everyone done with P/Q levels
#pragma unroll
    for (int k = 0; k < WPR; ++k) SA[y][k] = sk[k];
    // --- wait for this image's 16 edt tiles (device-scope acquire) ---
    if (t == 0) {
      while (__hip_atomic_load(&cnts[bi], __ATOMIC_ACQUIRE,
                               __HIP_MEMORY_SCOPE_AGENT) < 16u)
        __builtin_amdgcn_s_sleep(8);
    }
    __syncthreads();
    __threadfence();                      // acquire: invalidate stale L1/L2
    // --- rmax/rmin: coalesced float4 reads, skel bits broadcast from LDS ---
    const float* epx = edt + bi * NPIX;
    float vmax = 0.0f, vmin = 3.0e38f;
    for (int it2 = 0; it2 < 64; ++it2) {  // 64 iters x 1024 px
      int p0 = it2 * 1024 + t * 4;
      float4 d4 = *(const float4*)(epx + p0);
      int row = p0 >> 8;                  // 4 rows per iteration
      u64 w = SA[row][(p0 & 255) >> 6];   // per-16-lane uniform -> broadcast
      int sh = p0 & 63;                   // <= 60
      float ds[4] = {d4.x, d4.y, d4.z, d4.w};
#pragma unroll
      for (int j = 0; j < 4; ++j) {
        int bit = (int)((w >> (sh + j)) & 1ULL);
        float srad = bit ? ds[j] : 0.0f;  // == skel_radius (ref semantics)
        vmax = fmaxf(vmax, srad);
        vmin = fminf(vmin, srad);
      }
    }
    for (int o = 32; o > 0; o >>= 1) {
      vmax = fmaxf(vmax, __shfl_down(vmax, o, 64));
      vmin = fminf(vmin, __shfl_down(vmin, o, 64));
    }
    int wave = t >> 6, lane = t & 63;
    if (lane == 0) { smax[wave] = vmax; smin[wave] = vmin; }
    __syncthreads();
    if (t == 0) {
      float mx = smax[0], mn = smin[0];
      for (int wv = 1; wv < 4; ++wv) { mx = fmaxf(mx, smax[wv]); mn = fminf(mn, smin[wv]); }
      rmm_f[bi*2 + 0] = mx;
      rmm_f[bi*2 + 1] = mn;
    }
  } else {
    // --- EDT distances for tile (bi, xt), mask row read from global ---
    int bt = blockIdx.x - NSKEL;
    int bi = bt >> 4;                    // 0..7 = branch*4+img
    int xt = bt & 15;
    int x0 = xt * XT;
    int kx = x0 >> 6;                    // all tile columns in this u64 word
    // phase 1: thread = row y; horizontal EDT g via clz/ctz -> col2 = g^2
    {
      int y = t;
      const u64* row = mask_bits + bi*WPI + y*WPR;
      u64 z[WPR];
#pragma unroll
      for (int k = 0; k < WPR; ++k) z[k] = ~row[k];   // background bits
#pragma unroll
      for (int xx = 0; xx < XT; ++xx) {
        int x = x0 + xx;
        int bx = x & 63;
        int ld = 512;
        {
          u64 w = z[kx] & ((bx == 63) ? ~0ULL : ((1ULL << (bx+1)) - 1ULL));
          for (int k = kx; ; ) {
            if (w) { int pos = 63 - __builtin_clzll(w) + (k << 6); ld = x - pos; break; }
            if (--k < 0) break;
            w = z[k];
          }
        }
        int rd = 512;
        {
          u64 w = z[kx] & (~0ULL << bx);
          for (int k = kx; ; ) {
            if (w) { int pos = __builtin_ctzll(w) + (k << 6); rd = pos - x; break; }
            if (++k > WPR-1) break;
            w = z[k];
          }
        }
        int g = min(ld, rd);
        col2[y][xx] = (float)(g * g);
      }
    }
    __syncthreads();
    // phase 2: thread = (x in tile, ygrp of 16 rows); early-exit envelope
    int x  = t & (XT - 1);
    int yg = t >> 4;
#pragma unroll
    for (int j = 0; j < 16; ++j) {
      int y = yg * 16 + j;
      float best = col2[y][x];
      for (int k = 1; k < H; ++k) {
        float k2 = (float)(k * k);
        if (k2 >= best) break;           // no farther candidate can improve
        int ym = y - k, yq = y + k;
        if (ym >= 0) best = fminf(best, col2[ym][x] + k2);
        if (yq < H)  best = fminf(best, col2[yq][x] + k2);
      }
      edt[bi*NPIX + y*W + x0 + x] = sqrtf(best);
    }
    // --- handshake: stores drained by the barrier, release-fence, count ---
    __syncthreads();                     // emits s_waitcnt vmcnt(0) first
    if (t == 0) {
      __threadfence();                   // release: writeback XCD L2
      atomicAdd(&cnts[bi], 1u);          // device-scope
    }
  }
}

// ---------------------------------------------------------------------------
// K3: q terms + sums + in-kernel finalize. 256 blocks x 256 threads,
// 4 px/thread (round-0 proven structure + round-2 proven finalize tail).
// ---------------------------------------------------------------------------
__global__ void __launch_bounds__(256) final_kernel(
    const float* __restrict__ edt, const u64* __restrict__ mask_bits,
    const u64* __restrict__ skel_bits, const float* __restrict__ pp,
    const float* __restrict__ rmm_f, double* __restrict__ sums,
    unsigned* __restrict__ cnts, float* __restrict__ out) {
  int i0 = (blockIdx.x * 256 + threadIdx.x) * 4;  // 0..NTOT-1, step 4
  int img = i0 >> 16;
  int wi = i0 >> 6;
  int b0 = i0 & 63;                               // b0 <= 60: 4 bits same word
  u64 mw_t = mask_bits[wi];
  u64 sw_t = skel_bits[wi];
  u64 sw_p = skel_bits[WPB + wi];
  float4 d_t4 = *(const float4*)(edt + i0);
  float4 d_p4 = *(const float4*)(edt + NTOT + i0);
  float4 pp4  = *(const float4*)(pp + i0);
  float rmax_t = fmaxf(rmm_f[img*2 + 0], 1.0f);
  float rmin_t = fmaxf(rmm_f[img*2 + 1], 1.0f);
  float rmax_p = fmaxf(rmm_f[(4+img)*2 + 0], 1.0f);
  float rmin_p = fmaxf(rmm_f[(4+img)*2 + 1], 1.0f);
  float t1 = 0.f, t2 = 0.f, t3 = 0.f, t4 = 0.f;
  float dts[4] = {d_t4.x, d_t4.y, d_t4.z, d_t4.w};
  float dps[4] = {d_p4.x, d_p4.y, d_p4.z, d_p4.w};
  float pps[4] = {pp4.x, pp4.y, pp4.z, pp4.w};
#pragma unroll
  for (int j = 0; j < 4; ++j) {
    int b = b0 + j;
    // --- true branch (binary) ---
    int m_t = (int)((mw_t >> b) & 1ULL);
    int s_t = (int)((sw_t >> b) & 1ULL);
    float distances_t = m_t ? dts[j] : 0.0f;
    float skelrad_t   = s_t ? distances_t : 0.0f;
    float dmn_t = fminf(distances_t, rmax_t) / rmax_t;
    float srn_t = skelrad_t / rmax_t;
    float In_t  = s_t ? (rmax_t - skelrad_t + rmin_t) / rmax_t : 0.0f;
    float q_vl   = m_t ? dmn_t : 0.0f;
    float q_slvl = m_t ? srn_t : 0.0f;
    float q_sl   = s_t ? In_t  : 0.0f;
    // --- pred branch (probabilistic) ---
    int s_pb = (int)((sw_p >> b) & 1ULL);
    float ppv = pps[j];
    float skel_in_p = s_pb ? ppv : 0.0f;      // skel_pred_prob
    bool msk_p = ppv > 0.5f;
    bool sk_p  = skel_in_p > 0.5f;
    float distances_p = msk_p ? dps[j] : 0.0f;
    float skelrad_p   = sk_p ? distances_p : 0.0f;
    float dmn_p = fminf(distances_p, rmax_p) / rmax_p;
    float srn_p = skelrad_p / rmax_p;
    float In_p  = sk_p ? (rmax_p - skelrad_p + rmin_p) / rmax_p : 0.0f;
    float q_vp   = dmn_p * ppv;
    float q_spvp = srn_p * ppv;
    float q_sp   = In_p * skel_in_p;
    t1 += q_sp * q_vl;
    t2 += (q_spvp != 0.0f && q_slvl == 0.0f) ? q_spvp * q_sp : q_slvl * q_sp;
    t3 += q_sl * q_vp;
    t4 += (q_slvl != 0.0f && q_spvp == 0.0f) ? q_slvl * q_sl : q_spvp * q_sl;
  }
  for (int o = 32; o > 0; o >>= 1) {
    t1 += __shfl_down(t1, o, 64);
    t2 += __shfl_down(t2, o, 64);
    t3 += __shfl_down(t3, o, 64);
    t4 += __shfl_down(t4, o, 64);
  }
  __shared__ float part[4][4];
  int wave = threadIdx.x >> 6, lane = threadIdx.x & 63;
  if (lane == 0) { part[wave][0]=t1; part[wave][1]=t2; part[wave][2]=t3; part[wave][3]=t4; }
  __syncthreads();
  if (threadIdx.x == 0) {
    float a0=0,a1=0,a2=0,a3=0;
    for (int wv = 0; wv < 4; ++wv) {
      a0 += part[wv][0]; a1 += part[wv][1]; a2 += part[wv][2]; a3 += part[wv][3];
    }
    atomicAdd(&sums[0], (double)a0);
    atomicAdd(&sums[1], (double)a1);
    atomicAdd(&sums[2], (double)a2);
    atomicAdd(&sums[3], (double)a3);
    __threadfence();                    // publish sums before counting done
    unsigned c = atomicAdd(&cnts[8], 1u);
    if (c == NB3 - 1) {                 // last block finalizes (device-scope
      double s0 = atomicAdd(&sums[0], 0.0);   // atomic loads for coherence)
      double s1 = atomicAdd(&sums[1], 0.0);
      double s2 = atomicAdd(&sums[2], 0.0);
      double s3 = atomicAdd(&sums[3], 0.0);
      double wp  = (s0 + 1.0) / (s1 + 1.0);
      double wsn = (s2 + 1.0) / (s3 + 1.0);
      out[0] = (float)(1.0 - 2.0 * (wp * wsn) / (wp + wsn));
    }
  }
}

extern "C" void kernel_launch(void* const* d_in, const int* in_sizes, int n_in,
                              void* d_out, int out_size, void* d_ws, size_t ws_size,
                              hipStream_t stream) {
  (void)in_sizes; (void)n_in; (void)out_size; (void)ws_size;
  const float* y_pred = (const float*)d_in[0];
  const int*   y_true = (const int*)d_in[1];
  float* out = (float*)d_out;
  char* ws = (char*)d_ws;

  // workspace layout (bytes)
  float* pp        = (float*)(ws + 0);          // 262144 f  (1,048,576 B)
  float* edt       = (float*)(ws + 1048576);    // 524288 f  (2,097,152 B) [branch][img][y][x]
  u64*   mask_bits = (u64*)  (ws + 3145728);    // 8192 u64  (65,536 B)
  u64*   skel_bits = (u64*)  (ws + 3211264);    // 8192 u64  (65,536 B)
  float* rmm_f     = (float*)(ws + 3276800);    // 16 f
  double* sums     = (double*)(ws + 3276864);   // 4 d
  unsigned* cnts   = (unsigned*)(ws + 3276896); // cnts[0..7]=edt_done, cnts[8]=done

  prep_kernel<<<NTOT/256, 256, 0, stream>>>(y_pred, y_true, pp, mask_bits, sums, cnts);
  morpho_kernel<<<NB2, 256, 0, stream>>>(mask_bits, skel_bits, edt, rmm_f, cnts);
  final_kernel<<<NB3, 256, 0, stream>>>(edt, mask_bits, skel_bits, pp, rmm_f, sums, cnts, out);
}

// Round 4
// 90.030 us; speedup vs baseline: 2.1293x; 1.1407x over previous
//
#include <hip/hip_runtime.h>

typedef unsigned long long u64;

#define NIMG 4
#define H 256
#define W 256
#define NPIX (H*W)           // 65536 per image
#define NTOT (NIMG*NPIX)     // 262144
#define WPR 4                // u64 words per row (256 bits)
#define WPI (H*WPR)          // 1024 words per image
#define WPB (NIMG*WPI)       // 4096 words per branch
#define XT 16                // columns per edt tile block
#define NSKEL 8              // skeleton blocks (1 per branch-image)
#define NEDT 128             // edt tile blocks
#define NB2 (NSKEL+NEDT)     // 136 blocks: all co-resident (<=256 CUs)
#define NB3 (NTOT/1024)      // 256 blocks in final kernel

// ---------------------------------------------------------------------------
// Bit-parallel morphology helpers. Bit b of word k = pixel x = 64k+b.
// Erode = AND over cross; OOB=1.  Dilate = OR over 3x3 box; OOB=0.
// ---------------------------------------------------------------------------
__device__ __forceinline__ void erode_from(const u64 S[][WPR], int y, u64 out[WPR]) {
  u64 c[WPR], up[WPR], dn[WPR];
#pragma unroll
  for (int k = 0; k < WPR; ++k) {
    c[k]  = S[y][k];
    up[k] = (y > 0)     ? S[y-1][k] : ~0ULL;
    dn[k] = (y < H-1)   ? S[y+1][k] : ~0ULL;
  }
#pragma unroll
  for (int k = 0; k < WPR; ++k) {
    u64 l = (c[k] << 1) | ((k > 0)     ? (c[k-1] >> 63) : 1ULL);
    u64 r = (c[k] >> 1) | ((k < WPR-1) ? (c[k+1] << 63) : 0x8000000000000000ULL);
    out[k] = c[k] & up[k] & dn[k] & l & r;
  }
}

__device__ __forceinline__ void dilate_from(const u64 S[][WPR], int y, u64 out[WPR]) {
  u64 v[WPR];
#pragma unroll
  for (int k = 0; k < WPR; ++k) {
    u64 a = S[y][k];
    if (y > 0)   a |= S[y-1][k];
    if (y < H-1) a |= S[y+1][k];
    v[k] = a;
  }
#pragma unroll
  for (int k = 0; k < WPR; ++k) {
    u64 l = (v[k] << 1) | ((k > 0)     ? (v[k-1] >> 63) : 0ULL);
    u64 r = (v[k] >> 1) | ((k < WPR-1) ? (v[k+1] << 63) : 0ULL);
    out[k] = v[k] | l | r;
  }
}

// ---------------------------------------------------------------------------
// K1: prep — round-0 proven form (1 px/thread, NO loop: looped ballot chains
// were the round-2 disaster). pp = sigmoid(2*sigmoid(x)-1); pack yt and
// (pp>0.5) bitmasks. Block 0 inits rmm identities + sums + counters.
// ---------------------------------------------------------------------------
__global__ void __launch_bounds__(256) prep_kernel(
    const float* __restrict__ y_pred, const int* __restrict__ y_true,
    float* __restrict__ pp, u64* __restrict__ mask_bits,
    unsigned* __restrict__ rmm_u, double* __restrict__ sums,
    unsigned* __restrict__ cnts) {
  if (blockIdx.x == 0) {
    if (threadIdx.x < 16) rmm_u[threadIdx.x] = (threadIdx.x & 1) ? 0x7F800000u : 0u; // min:+inf, max:0
    else if (threadIdx.x < 20) sums[threadIdx.x - 16] = 0.0;
    else if (threadIdx.x < 29) cnts[threadIdx.x - 20] = 0u;  // 8 skel flags + done
  }
  int i = blockIdx.x * 256 + threadIdx.x;
  float x = y_pred[i];
  float p = 1.0f / (1.0f + expf(-x));
  float q = 1.0f / (1.0f + expf(-(2.0f * p - 1.0f)));
  pp[i] = q;
  u64 bt = __ballot(y_true[i] > 0);
  u64 bp = __ballot(q > 0.5f);
  if ((threadIdx.x & 63) == 0) {
    mask_bits[i >> 6] = bt;          // branch 0: true mask
    mask_bits[WPB + (i >> 6)] = bp;  // branch 1: pred hard mask (pp>0.5)
  }
}

// ---------------------------------------------------------------------------
// K2: morpho — 136 blocks, skel || EDT with the REVERSED handshake:
//  blocks 0..7   (producers): 10-iter bit-packed soft_skel in LDS ->
//                 skel_bits; ONE release fence per image (8 wbl2 total, vs
//                 128 in round 3); set flag. Then done — no rmm tail.
//  blocks 8..135 (consumers): EDT phase1+2 (proven), distances kept in
//                 REGISTERS; then poll this image's flag (relaxed agent load
//                 — skel at ~6us finishes before EDT's ~10us envelope, so
//                 near-zero spin), stage ONE skel word per thread via
//                 agent-scope sc1 loads (bypass stale L2; producer release
//                 pushed data to LLC), and run the baseline's proven fused
//                 rmax/rmin atomicMax/Min. No acquire invalidate, no re-read.
// ---------------------------------------------------------------------------
__global__ void __launch_bounds__(256, 1) morpho_kernel(
    const u64* __restrict__ mask_bits, u64* __restrict__ skel_bits,
    float* __restrict__ edt, unsigned* __restrict__ rmm_u,
    unsigned* __restrict__ cnts) {
  __shared__ u64 SA[H][WPR];
  __shared__ u64 SB[H][WPR];
  __shared__ float col2[H][XT + 1];   // pad 17: 2-way aliasing free on gfx950
  __shared__ u64 srow[H];
  __shared__ float smax[4], smin[4];
  int t = threadIdx.x;

  if (blockIdx.x < NSKEL) {
    // --- soft_skel, bit-packed, 1 thread per row, ONE barrier per level ---
    int bi = blockIdx.x;
    int y = t;
    int base = bi * WPI;
    u64 a[WPR], cur[WPR], e[WPR], d[WPR], sk[WPR];
#pragma unroll
    for (int k = 0; k < WPR; ++k) { a[k] = mask_bits[base + y*WPR + k]; SA[y][k] = a[k]; }
    __syncthreads();
    erode_from(SA, y, e);                 // E1 = erode(a)
#pragma unroll
    for (int k = 0; k < WPR; ++k) SB[y][k] = e[k];
    __syncthreads();                      // SB visible; all SA reads complete
    dilate_from(SB, y, d);                // open(a)
#pragma unroll
    for (int k = 0; k < WPR; ++k) { sk[k] = a[k] & ~d[k]; cur[k] = e[k]; }
    u64 (*P)[WPR] = SB;                   // current erosion level E_k
    u64 (*Q)[WPR] = SA;                   // dead buffer
    for (int it = 0; it < 10; ++it) {     // levels 1..10
      erode_from(P, y, e);                // E_{k+1}
#pragma unroll
      for (int k = 0; k < WPR; ++k) Q[y][k] = e[k];   // overwrite dead data
      __syncthreads();                    // publish Q; P reads all done
      dilate_from(Q, y, d);               // open(E_k)
#pragma unroll
      for (int k = 0; k < WPR; ++k) { sk[k] |= cur[k] & ~d[k]; cur[k] = e[k]; }
      u64 (*T)[WPR] = P; P = Q; Q = T;
    }
#pragma unroll
    for (int k = 0; k < WPR; ++k) skel_bits[base + y*WPR + k] = sk[k];
    __syncthreads();                      // all stores issued + vmcnt drained
    if (t == 0) {
      __threadfence();                    // release: writeback this XCD's L2
      atomicAdd(&cnts[bi], 1u);          // publish flag (device scope -> LLC)
    }
  } else {
    // --- EDT distances for tile (bi, xt), mask rows from global (L2-hot) ---
    int bt = blockIdx.x - NSKEL;
    int bi = bt >> 4;                    // 0..7 = branch*4+img
    int xt = bt & 15;
    int x0 = xt * XT;
    int kx = x0 >> 6;                    // all tile columns in this u64 word
    int sh0 = x0 & 63;
    // phase 1: thread = row y; horizontal EDT g via clz/ctz -> col2 = g^2
    {
      int y = t;
      const u64* row = mask_bits + bi*WPI + y*WPR;
      u64 z[WPR];
#pragma unroll
      for (int k = 0; k < WPR; ++k) z[k] = ~row[k];   // background bits
#pragma unroll
      for (int xx = 0; xx < XT; ++xx) {
        int x = x0 + xx;
        int bx = x & 63;
        int ld = 512;
        {
          u64 w = z[kx] & ((bx == 63) ? ~0ULL : ((1ULL << (bx+1)) - 1ULL));
          for (int k = kx; ; ) {
            if (w) { int pos = 63 - __builtin_clzll(w) + (k << 6); ld = x - pos; break; }
            if (--k < 0) break;
            w = z[k];
          }
        }
        int rd = 512;
        {
          u64 w = z[kx] & (~0ULL << bx);
          for (int k = kx; ; ) {
            if (w) { int pos = __builtin_ctzll(w) + (k << 6); rd = pos - x; break; }
            if (++k > WPR-1) break;
            w = z[k];
          }
        }
        int g = min(ld, rd);
        col2[y][xx] = (float)(g * g);
      }
    }
    __syncthreads();
    // phase 2: thread = (x, ygrp); early-exit envelope; dist kept in regs
    int x  = t & (XT - 1);
    int yg = t >> 4;
    float dist_r[16];
#pragma unroll
    for (int j = 0; j < 16; ++j) {
      int y = yg * 16 + j;
      float best = col2[y][x];
      for (int k = 1; k < H; ++k) {
        float k2 = (float)(k * k);
        if (k2 >= best) break;           // no farther candidate can improve
        int ym = y - k, yq = y + k;
        if (ym >= 0) best = fminf(best, col2[ym][x] + k2);
        if (yq < H)  best = fminf(best, col2[yq][x] + k2);
      }
      float dist = sqrtf(best);
      dist_r[j] = dist;
      edt[bi*NPIX + y*W + x0 + x] = dist;
    }
    // --- handshake: wait for this image's skel flag (near-zero spin) ---
    if (t == 0) {
      while (__hip_atomic_load(&cnts[bi], __ATOMIC_RELAXED,
                               __HIP_MEMORY_SCOPE_AGENT) == 0u)
        __builtin_amdgcn_s_sleep(2);
    }
    __syncthreads();
    // stage skel words: 1 sc1 load/thread (bypasses stale L2 -> LLC)
    srow[t] = __hip_atomic_load(&skel_bits[bi*WPI + t*WPR + kx],
                                __ATOMIC_RELAXED, __HIP_MEMORY_SCOPE_AGENT);
    __syncthreads();
    // --- fused rmax/rmin (baseline-proven tail, skel word from LDS) ---
    float vmax = 0.0f, vmin = 3.0e38f;
#pragma unroll
    for (int j = 0; j < 16; ++j) {
      int y = yg * 16 + j;
      u64 sw = srow[y];
      int sb = (int)((sw >> (sh0 + x)) & 1ULL);
      float srad = sb ? dist_r[j] : 0.0f; // == skel_radius for both branches
      vmax = fmaxf(vmax, srad);
      vmin = fminf(vmin, srad);
    }
    for (int o = 32; o > 0; o >>= 1) {
      vmax = fmaxf(vmax, __shfl_down(vmax, o, 64));
      vmin = fminf(vmin, __shfl_down(vmin, o, 64));
    }
    int wave = t >> 6, lane = t & 63;
    if (lane == 0) { smax[wave] = vmax; smin[wave] = vmin; }
    __syncthreads();
    if (t == 0) {
      float mx = smax[0], mn = smin[0];
      for (int wv = 1; wv < 4; ++wv) { mx = fmaxf(mx, smax[wv]); mn = fminf(mn, smin[wv]); }
      atomicMax(&rmm_u[bi*2 + 0], __float_as_uint(mx));
      atomicMin(&rmm_u[bi*2 + 1], __float_as_uint(mn));
    }
  }
}

// ---------------------------------------------------------------------------
// K3: q terms + sums + in-kernel finalize (proven). 256 blocks x 256 threads,
// 4 px/thread — round-0 body + rounds-2/3 proven last-block tail.
// ---------------------------------------------------------------------------
__global__ void __launch_bounds__(256) final_kernel(
    const float* __restrict__ edt, const u64* __restrict__ mask_bits,
    const u64* __restrict__ skel_bits, const float* __restrict__ pp,
    const unsigned* __restrict__ rmm_u, double* __restrict__ sums,
    unsigned* __restrict__ cnts, float* __restrict__ out) {
  int i0 = (blockIdx.x * 256 + threadIdx.x) * 4;  // 0..NTOT-1, step 4
  int img = i0 >> 16;
  int wi = i0 >> 6;
  int b0 = i0 & 63;                               // b0 <= 60: 4 bits same word
  u64 mw_t = mask_bits[wi];
  u64 sw_t = skel_bits[wi];
  u64 sw_p = skel_bits[WPB + wi];
  float4 d_t4 = *(const float4*)(edt + i0);
  float4 d_p4 = *(const float4*)(edt + NTOT + i0);
  float4 pp4  = *(const float4*)(pp + i0);
  float rmax_t = fmaxf(__uint_as_float(rmm_u[img*2 + 0]), 1.0f);
  float rmin_t = fmaxf(__uint_as_float(rmm_u[img*2 + 1]), 1.0f);
  float rmax_p = fmaxf(__uint_as_float(rmm_u[(4+img)*2 + 0]), 1.0f);
  float rmin_p = fmaxf(__uint_as_float(rmm_u[(4+img)*2 + 1]), 1.0f);
  float t1 = 0.f, t2 = 0.f, t3 = 0.f, t4 = 0.f;
  float dts[4] = {d_t4.x, d_t4.y, d_t4.z, d_t4.w};
  float dps[4] = {d_p4.x, d_p4.y, d_p4.z, d_p4.w};
  float pps[4] = {pp4.x, pp4.y, pp4.z, pp4.w};
#pragma unroll
  for (int j = 0; j < 4; ++j) {
    int b = b0 + j;
    // --- true branch (binary) ---
    int m_t = (int)((mw_t >> b) & 1ULL);
    int s_t = (int)((sw_t >> b) & 1ULL);
    float distances_t = m_t ? dts[j] : 0.0f;
    float skelrad_t   = s_t ? distances_t : 0.0f;
    float dmn_t = fminf(distances_t, rmax_t) / rmax_t;
    float srn_t = skelrad_t / rmax_t;
    float In_t  = s_t ? (rmax_t - skelrad_t + rmin_t) / rmax_t : 0.0f;
    float q_vl   = m_t ? dmn_t : 0.0f;
    float q_slvl = m_t ? srn_t : 0.0f;
    float q_sl   = s_t ? In_t  : 0.0f;
    // --- pred branch (probabilistic) ---
    int s_pb = (int)((sw_p >> b) & 1ULL);
    float ppv = pps[j];
    float skel_in_p = s_pb ? ppv : 0.0f;      // skel_pred_prob
    bool msk_p = ppv > 0.5f;
    bool sk_p  = skel_in_p > 0.5f;
    float distances_p = msk_p ? dps[j] : 0.0f;
    float skelrad_p   = sk_p ? distances_p : 0.0f;
    float dmn_p = fminf(distances_p, rmax_p) / rmax_p;
    float srn_p = skelrad_p / rmax_p;
    float In_p  = sk_p ? (rmax_p - skelrad_p + rmin_p) / rmax_p : 0.0f;
    float q_vp   = dmn_p * ppv;
    float q_spvp = srn_p * ppv;
    float q_sp   = In_p * skel_in_p;
    t1 += q_sp * q_vl;
    t2 += (q_spvp != 0.0f && q_slvl == 0.0f) ? q_spvp * q_sp : q_slvl * q_sp;
    t3 += q_sl * q_vp;
    t4 += (q_slvl != 0.0f && q_spvp == 0.0f) ? q_slvl * q_sl : q_spvp * q_sl;
  }
  for (int o = 32; o > 0; o >>= 1) {
    t1 += __shfl_down(t1, o, 64);
    t2 += __shfl_down(t2, o, 64);
    t3 += __shfl_down(t3, o, 64);
    t4 += __shfl_down(t4, o, 64);
  }
  __shared__ float part[4][4];
  int wave = threadIdx.x >> 6, lane = threadIdx.x & 63;
  if (lane == 0) { part[wave][0]=t1; part[wave][1]=t2; part[wave][2]=t3; part[wave][3]=t4; }
  __syncthreads();
  if (threadIdx.x == 0) {
    float a0=0,a1=0,a2=0,a3=0;
    for (int wv = 0; wv < 4; ++wv) {
      a0 += part[wv][0]; a1 += part[wv][1]; a2 += part[wv][2]; a3 += part[wv][3];
    }
    atomicAdd(&sums[0], (double)a0);
    atomicAdd(&sums[1], (double)a1);
    atomicAdd(&sums[2], (double)a2);
    atomicAdd(&sums[3], (double)a3);
    __threadfence();                    // publish sums before counting done
    unsigned c = atomicAdd(&cnts[8], 1u);
    if (c == NB3 - 1) {                 // last block finalizes (device-scope
      double s0 = atomicAdd(&sums[0], 0.0);   // atomic loads for coherence)
      double s1 = atomicAdd(&sums[1], 0.0);
      double s2 = atomicAdd(&sums[2], 0.0);
      double s3 = atomicAdd(&sums[3], 0.0);
      double wp  = (s0 + 1.0) / (s1 + 1.0);
      double wsn = (s2 + 1.0) / (s3 + 1.0);
      out[0] = (float)(1.0 - 2.0 * (wp * wsn) / (wp + wsn));
    }
  }
}

extern "C" void kernel_launch(void* const* d_in, const int* in_sizes, int n_in,
                              void* d_out, int out_size, void* d_ws, size_t ws_size,
                              hipStream_t stream) {
  (void)in_sizes; (void)n_in; (void)out_size; (void)ws_size;
  const float* y_pred = (const float*)d_in[0];
  const int*   y_true = (const int*)d_in[1];
  float* out = (float*)d_out;
  char* ws = (char*)d_ws;

  // workspace layout (bytes)
  float* pp        = (float*)(ws + 0);          // 262144 f  (1,048,576 B)
  float* edt       = (float*)(ws + 1048576);    // 524288 f  (2,097,152 B) [branch][img][y][x]
  u64*   mask_bits = (u64*)  (ws + 3145728);    // 8192 u64  (65,536 B)
  u64*   skel_bits = (u64*)  (ws + 3211264);    // 8192 u64  (65,536 B)
  unsigned* rmm_u  = (unsigned*)(ws + 3276800); // 16 u32
  double* sums     = (double*)(ws + 3276864);   // 4 d
  unsigned* cnts   = (unsigned*)(ws + 3276896); // cnts[0..7]=skel flags, cnts[8]=done

  prep_kernel<<<NTOT/256, 256, 0, stream>>>(y_pred, y_true, pp, mask_bits, rmm_u, sums, cnts);
  morpho_kernel<<<NB2, 256, 0, stream>>>(mask_bits, skel_bits, edt, rmm_u, cnts);
  final_kernel<<<NB3, 256, 0, stream>>>(edt, mask_bits, skel_bits, pp, rmm_u, sums, cnts, out);
}